// Round 4
// baseline (516.186 us; speedup 1.0000x reference)
//
#include <hip/hip_runtime.h>
#include <cstdint>
#include <cstddef>

typedef __attribute__((ext_vector_type(8))) short short8;
typedef __attribute__((ext_vector_type(4))) float f32x4;

// ---------- helpers ----------
__device__ __forceinline__ unsigned short f2bf(float x) {
  union { float f; unsigned u; } v; v.f = x;
  unsigned r = (v.u + 0x7FFFu + ((v.u >> 16) & 1u)) >> 16;
  return (unsigned short)r;
}
__device__ __forceinline__ float bf2f(unsigned short u) {
  union { unsigned u; float f; } v; v.u = ((unsigned)u) << 16;
  return v.f;
}

#define GLOAD16(g, l)                                                    \
  __builtin_amdgcn_global_load_lds(                                      \
      (const __attribute__((address_space(1))) unsigned int*)(g),        \
      (__attribute__((address_space(3))) unsigned int*)(l), 16, 0, 0)

// ---------- f32 -> bf16 conversion (memory-bound) ----------
__global__ __launch_bounds__(256) void cvt_f32_bf16(
    const float* __restrict__ in, unsigned short* __restrict__ out, long n) {
  long i = ((long)blockIdx.x * 256 + threadIdx.x) * 8;
  if (i >= n) return;
  const float4* p = (const float4*)(in + i);
  float4 a = p[0], b = p[1];
  short8 r;
  r[0] = (short)f2bf(a.x); r[1] = (short)f2bf(a.y);
  r[2] = (short)f2bf(a.z); r[3] = (short)f2bf(a.w);
  r[4] = (short)f2bf(b.x); r[5] = (short)f2bf(b.y);
  r[6] = (short)f2bf(b.z); r[7] = (short)f2bf(b.w);
  *(short8*)(out + i) = r;
}

// ---------- gemm_bt256: C[b][m,n] = scale * sum_k A[b][m,k]*B[b][n,k] ----
// 256x256 tile, 8 waves (2M x 4N), BK=32, 4-deep circular LDS pipeline
// (depth-3 prefetch, counted vmcnt(12) -> drain hidden under ~3 compute
// iterations ~= HBM latency). Raw s_barrier, setprio around MFMA cluster.
// LDS swizzle (BK=32, 4 x 16B chunks/row): slot = chunk ^ ((row>>1)&3);
// inverse applied on the global source address (2-way bank alias = free).
// Requires M%256==0, N%256==0, K%32==0 (and K/32 >= 4), gridDim.x%8==0.
template <bool OUT_BF16>
__global__ __launch_bounds__(512, 2) void gemm_bt256(
    const unsigned short* __restrict__ A, int lda, size_t asb,
    const unsigned short* __restrict__ B, int ldb, size_t bsb,
    void* __restrict__ C, int ldc, size_t csb,
    int nbn, int K, float scale) {
  __shared__ unsigned short As[4][256 * 32];
  __shared__ unsigned short Bs[4][256 * 32];

  A += (size_t)blockIdx.y * asb;
  B += (size_t)blockIdx.y * bsb;
  char* Cb = (char*)C + (size_t)blockIdx.y * csb * (OUT_BF16 ? 2 : 4);

  // XCD-aware block swizzle (gridDim.x multiple of 8)
  unsigned bid = blockIdx.x;
  unsigned cpx = gridDim.x >> 3;
  unsigned swz = (bid & 7u) * cpx + (bid >> 3);
  int bm = (int)(swz / (unsigned)nbn);
  int bn = (int)(swz % (unsigned)nbn);
  int m0 = bm * 256, n0 = bn * 256;

  int t512 = threadIdx.x;
  int lane = t512 & 63, wid = t512 >> 6;
  int wm = wid >> 2, wn = wid & 3;           // 2 x 4 wave grid
  int l15 = lane & 15, l4 = lane >> 4;

  // staging: instr i (0/1), thread t: chunk = i*512+t; row = i*128 + (t>>2);
  // LDS slot = t&3 (linear dest); global chunk g = (t&3) ^ ((t>>3)&3)
  // (since (row>>1)&3 == (t>>3)&3 for both i, as i*128>>1 = 64*i ≡ 0 mod 4).
  int srow = t512 >> 2;
  int g = (t512 & 3) ^ ((t512 >> 3) & 3);
  const unsigned short* pa = A + (size_t)(m0 + srow) * lda + g * 8;
  const unsigned short* pb = B + (size_t)(n0 + srow) * ldb + g * 8;

  f32x4 acc[8][4] = {};

  const int NT = K >> 5;  // K/32 tiles

#define STAGE(jj)                                                         \
  do {                                                                    \
    int _b = (jj) & 3;                                                    \
    int _k0 = (jj) << 5;                                                  \
    GLOAD16(pa + _k0, (char*)As[_b] + t512 * 16);                         \
    GLOAD16(pa + (size_t)128 * lda + _k0,                                 \
            (char*)As[_b] + 8192 + t512 * 16);                            \
    GLOAD16(pb + _k0, (char*)Bs[_b] + t512 * 16);                         \
    GLOAD16(pb + (size_t)128 * ldb + _k0,                                 \
            (char*)Bs[_b] + 8192 + t512 * 16);                            \
  } while (0)

  // prologue: stage tiles 0,1,2
  STAGE(0);
  STAGE(1);
  STAGE(2);

  for (int j = 0; j < NT; ++j) {
    // barrier A: all waves done reading buf[(j+3)&3]'s old tile (j-1)
    __builtin_amdgcn_s_barrier();
    int rem = NT - 1 - j;
    if (rem >= 3) {
      STAGE(j + 3);
      asm volatile("s_waitcnt vmcnt(12)" ::: "memory");
    } else if (rem == 2) {
      asm volatile("s_waitcnt vmcnt(8)" ::: "memory");
    } else if (rem == 1) {
      asm volatile("s_waitcnt vmcnt(4)" ::: "memory");
    } else {
      asm volatile("s_waitcnt vmcnt(0)" ::: "memory");
    }
    // barrier B: every wave's tile-j loads have landed
    __builtin_amdgcn_s_barrier();

    const char* Ab = (const char*)As[j & 3];
    const char* Bb = (const char*)Bs[j & 3];

    short8 bfv[4];
#pragma unroll
    for (int ni = 0; ni < 4; ni++) {
      int r = wn * 64 + ni * 16 + l15;
      int slot = l4 ^ ((r >> 1) & 3);
      bfv[ni] = *(const short8*)(Bb + r * 64 + slot * 16);
    }
    short8 afv[8];
#pragma unroll
    for (int mi = 0; mi < 8; mi++) {
      int r = wm * 128 + mi * 16 + l15;
      int slot = l4 ^ ((r >> 1) & 3);
      afv[mi] = *(const short8*)(Ab + r * 64 + slot * 16);
    }
    asm volatile("s_waitcnt lgkmcnt(0)" ::: "memory");
    __builtin_amdgcn_sched_barrier(0);
    __builtin_amdgcn_s_setprio(1);
#pragma unroll
    for (int mi = 0; mi < 8; mi++)
#pragma unroll
      for (int ni = 0; ni < 4; ni++)
        acc[mi][ni] = __builtin_amdgcn_mfma_f32_16x16x32_bf16(
            afv[mi], bfv[ni], acc[mi][ni], 0, 0, 0);
    __builtin_amdgcn_s_setprio(0);
  }
#undef STAGE

  // epilogue
#pragma unroll
  for (int mi = 0; mi < 8; mi++)
#pragma unroll
    for (int ni = 0; ni < 4; ni++)
#pragma unroll
      for (int j = 0; j < 4; j++) {
        int row = m0 + wm * 128 + mi * 16 + l4 * 4 + j;
        int col = n0 + wn * 64 + ni * 16 + l15;
        float val = acc[mi][ni][j] * scale;
        if constexpr (OUT_BF16)
          ((unsigned short*)Cb)[(size_t)row * ldc + col] = f2bf(val);
        else
          ((float*)Cb)[(size_t)row * ldc + col] = val;
      }
}

// ---------- row softmax over bf16 matrix, in place ----------
__global__ __launch_bounds__(256) void softmax_rows(unsigned short* S, int ncols) {
  __shared__ float red[8];
  int row = blockIdx.x;
  unsigned short* p = S + (size_t)row * ncols;
  int t = threadIdx.x;
  int lane = t & 63, wid = t >> 6;

  short8 h0 = ((short8*)p)[t * 2];
  short8 h1 = ((short8*)p)[t * 2 + 1];
  float v[16];
#pragma unroll
  for (int j = 0; j < 8; j++) {
    v[j] = bf2f((unsigned short)h0[j]);
    v[8 + j] = bf2f((unsigned short)h1[j]);
  }
  float m = v[0];
#pragma unroll
  for (int j = 1; j < 16; j++) m = fmaxf(m, v[j]);
#pragma unroll
  for (int off = 1; off < 64; off <<= 1) m = fmaxf(m, __shfl_xor(m, off));
  if (lane == 0) red[wid] = m;
  __syncthreads();
  m = fmaxf(fmaxf(red[0], red[1]), fmaxf(red[2], red[3]));

  float e[16], s = 0.f;
#pragma unroll
  for (int j = 0; j < 16; j++) { e[j] = __expf(v[j] - m); s += e[j]; }
#pragma unroll
  for (int off = 1; off < 64; off <<= 1) s += __shfl_xor(s, off);
  if (lane == 0) red[4 + wid] = s;
  __syncthreads();
  float inv = 1.0f / (red[4] + red[5] + red[6] + red[7]);

  short8 o0, o1;
#pragma unroll
  for (int j = 0; j < 8; j++) {
    o0[j] = (short)f2bf(e[j] * inv);
    o1[j] = (short)f2bf(e[8 + j] * inv);
  }
  ((short8*)p)[t * 2] = o0;
  ((short8*)p)[t * 2 + 1] = o1;
}

// ---------- launcher ----------
extern "C" void kernel_launch(void* const* d_in, const int* in_sizes, int n_in,
                              void* d_out, int out_size, void* d_ws, size_t ws_size,
                              hipStream_t stream) {
  (void)in_sizes; (void)n_in; (void)out_size;
  const float* x  = (const float*)d_in[0];
  const float* Wq = (const float*)d_in[1];
  const float* Wk = (const float*)d_in[2];
  const float* Wv = (const float*)d_in[3];
  float* out = (float*)d_out;

  const int Bn = 4, S = 4096, D = 1024;
  const size_t MS = (size_t)Bn * S;  // 16384
  const float scale = 0.03125f;      // 1/sqrt(1024)

  // ---- workspace layout ----
  char* ws = (char*)d_ws;
  unsigned short* QKb = (unsigned short*)ws; ws += MS * 2048 * 2;        // 64 MiB
  unsigned short* VTb = (unsigned short*)ws; ws += MS * D * 2;           // 32 MiB
  unsigned short* Sreg = (unsigned short*)ws;
  const size_t s4_bytes = (size_t)Bn * S * S * 2;   // 128 MiB
  const size_t s1_bytes = (size_t)S * S * 2;        // 32 MiB
  size_t head = (size_t)(ws - (char*)d_ws);
  bool batched = ws_size >= head + s4_bytes + 6u * 1024 * 1024;
  ws += batched ? s4_bytes : s1_bytes;
  unsigned short* wqkb = (unsigned short*)ws; ws += (size_t)2048 * D * 2;
  unsigned short* wvb  = (unsigned short*)ws;
  unsigned short* xb = Sreg;  // alias: xb dead before any scores write

  // convert inputs to bf16
  cvt_f32_bf16<<<8192, 256, 0, stream>>>(x, xb, (long)MS * D);
  cvt_f32_bf16<<<512, 256, 0, stream>>>(Wq, wqkb, (long)D * D);
  cvt_f32_bf16<<<512, 256, 0, stream>>>(Wk, wqkb + (size_t)D * D, (long)D * D);
  cvt_f32_bf16<<<512, 256, 0, stream>>>(Wv, wvb, (long)D * D);

  // QK = x @ [Wq;Wk]^T  (M=16384, N=2048, K=1024)
  gemm_bt256<true><<<dim3(512, 1), 512, 0, stream>>>(
      xb, D, 0, wqkb, D, 0, QKb, 2048, 0, 8, D, 1.0f);
  // VT = Wv @ x^T  (M=1024, N=16384, K=1024) -> VTb [1024,16384]
  gemm_bt256<true><<<dim3(256, 1), 512, 0, stream>>>(
      wvb, D, 0, xb, D, 0, VTb, (int)MS, 0, 64, D, 1.0f);

  if (batched) {
    // scores[b] = Q_b K_b^T * scale  (M=N=4096, K=1024)
    gemm_bt256<true><<<dim3(256, Bn), 512, 0, stream>>>(
        QKb, 2048, (size_t)S * 2048,
        QKb + 1024, 2048, (size_t)S * 2048,
        Sreg, S, (size_t)S * S, 16, D, scale);
    softmax_rows<<<(int)MS, 256, 0, stream>>>(Sreg, S);
    // out[b] = P_b @ V_b  (M=4096, N=1024, K=4096)
    gemm_bt256<false><<<dim3(64, Bn), 512, 0, stream>>>(
        Sreg, S, (size_t)S * S,
        VTb, (int)MS, (size_t)S,
        out, D, (size_t)S * D, 4, S, 1.0f);
  } else {
    for (int b = 0; b < Bn; b++) {
      const unsigned short* Qx = QKb + (size_t)b * S * 2048;
      const unsigned short* Kx = Qx + 1024;
      gemm_bt256<true><<<dim3(256, 1), 512, 0, stream>>>(
          Qx, 2048, 0, Kx, 2048, 0, Sreg, S, 0, 16, D, scale);
      softmax_rows<<<S, 256, 0, stream>>>(Sreg, S);
      gemm_bt256<false><<<dim3(64, 1), 512, 0, stream>>>(
          Sreg, S, 0, VTb + (size_t)b * S, (int)MS, 0,
          out + (size_t)b * S * D, D, 0, 4, S, 1.0f);
    }
  }
}

// Round 5
// 455.440 us; speedup vs baseline: 1.1334x; 1.1334x over previous
//
#include <hip/hip_runtime.h>
#include <cstdint>
#include <cstddef>

typedef __attribute__((ext_vector_type(8))) short short8;
typedef __attribute__((ext_vector_type(4))) float f32x4;

// ---------- helpers ----------
__device__ __forceinline__ unsigned short f2bf(float x) {
  union { float f; unsigned u; } v; v.f = x;
  unsigned r = (v.u + 0x7FFFu + ((v.u >> 16) & 1u)) >> 16;
  return (unsigned short)r;
}

#define GLOAD16(g, l)                                                    \
  __builtin_amdgcn_global_load_lds(                                      \
      (const __attribute__((address_space(1))) unsigned int*)(g),        \
      (__attribute__((address_space(3))) unsigned int*)(l), 16, 0, 0)

// ---------- f32 -> bf16 conversion (memory-bound) ----------
__global__ __launch_bounds__(256) void cvt_f32_bf16(
    const float* __restrict__ in, unsigned short* __restrict__ out, long n) {
  long i = ((long)blockIdx.x * 256 + threadIdx.x) * 8;
  if (i >= n) return;
  const float4* p = (const float4*)(in + i);
  float4 a = p[0], b = p[1];
  short8 r;
  r[0] = (short)f2bf(a.x); r[1] = (short)f2bf(a.y);
  r[2] = (short)f2bf(a.z); r[3] = (short)f2bf(a.w);
  r[4] = (short)f2bf(b.x); r[5] = (short)f2bf(b.y);
  r[6] = (short)f2bf(b.z); r[7] = (short)f2bf(b.w);
  *(short8*)(out + i) = r;
}

// ---------- gemm_bt256: C[b][m,n] = f( sum_k A[b][m,k]*B[b][n,k] ) -------
// MODE 1: bf16 out (val*scale)
// MODE 2: bf16 out, exp(val*scale)            [scores: fused softmax-numerator]
// MODE 3: f32 out, val / rowsum(A)            [PV: fused softmax-denominator,
//         rowsum computed via extra MFMAs against an all-ones B fragment]
// 256x256 tile, 8 waves (2M x 4N), BK=64, double-buffered LDS (128 KiB),
// counted vmcnt(8): next tile's 8 loads stay in flight across barriers.
// Compute body is compiler-scheduled (no lgkmcnt asm) so ds_read and MFMA
// pipes overlap; sched_barrier(0) before barrier A pins the body.
// LDS swizzle: 16B slot ^= (row&7); inverse applied on global source.
// Requires M%256==0, N%256==0, K%64==0, gridDim.x%8==0.
template <int MODE>
__global__ __launch_bounds__(512, 2) void gemm_bt256(
    const unsigned short* __restrict__ A, int lda, size_t asb,
    const unsigned short* __restrict__ B, int ldb, size_t bsb,
    void* __restrict__ C, int ldc, size_t csb,
    int nbn, int K, float scale) {
  __shared__ unsigned short As[2][256 * 64];
  __shared__ unsigned short Bs[2][256 * 64];

  A += (size_t)blockIdx.y * asb;
  B += (size_t)blockIdx.y * bsb;
  char* Cb = (char*)C + (size_t)blockIdx.y * csb * (MODE == 3 ? 4 : 2);

  // XCD-aware block swizzle (gridDim.x multiple of 8)
  unsigned bid = blockIdx.x;
  unsigned cpx = gridDim.x >> 3;
  unsigned swz = (bid & 7u) * cpx + (bid >> 3);
  int bm = (int)(swz / (unsigned)nbn);
  int bn = (int)(swz % (unsigned)nbn);
  int m0 = bm * 256, n0 = bn * 256;

  int t512 = threadIdx.x;
  int lane = t512 & 63, wid = t512 >> 6;
  int wm = wid >> 2, wn = wid & 3;           // 2 x 4 wave grid
  int l15 = lane & 15, l4 = lane >> 4;

  // staging: thread t handles 16B chunks at rows srow+{0,64,128,192};
  // LDS slot = t&7 (linear dest), global chunk = slot ^ (srow&7).
  int srow = t512 >> 3;
  int g = (t512 & 7) ^ ((t512 >> 3) & 7);
  const unsigned short* pa = A + (size_t)(m0 + srow) * lda + g * 8;
  const unsigned short* pb = B + (size_t)(n0 + srow) * ldb + g * 8;

  f32x4 acc[8][4] = {};
  f32x4 rsum[8] = {};
  short8 ones;
#pragma unroll
  for (int e = 0; e < 8; e++) ones[e] = (short)0x3F80;  // bf16 1.0

  const int NT = K >> 6;

#define STAGE(jj, buf)                                                    \
  do {                                                                    \
    int _k0 = (jj) << 6;                                                  \
    _Pragma("unroll") for (int i = 0; i < 4; i++)                         \
        GLOAD16(pa + (size_t)(i * 64) * lda + _k0,                        \
                (char*)As[buf] + i * 8192 + t512 * 16);                   \
    _Pragma("unroll") for (int i = 0; i < 4; i++)                         \
        GLOAD16(pb + (size_t)(i * 64) * ldb + _k0,                        \
                (char*)Bs[buf] + i * 8192 + t512 * 16);                   \
  } while (0)

  // prologue: stage tile 0 into buffer 0
  STAGE(0, 0);

  for (int j = 0; j < NT; ++j) {
    int cur = j & 1;
    // pin all of iteration j-1's reads/MFMAs before the stage below
    __builtin_amdgcn_sched_barrier(0);
    // barrier A: all waves done with buf[cur^1] (tile j-1)
    __builtin_amdgcn_s_barrier();
    if (j + 1 < NT) {
      STAGE(j + 1, cur ^ 1);
      // wait ONLY for tile j's 8 loads; the 8 just issued stay in flight
      asm volatile("s_waitcnt vmcnt(8)" ::: "memory");
    } else {
      asm volatile("s_waitcnt vmcnt(0)" ::: "memory");
    }
    // barrier B: every wave's tile-j loads have landed
    __builtin_amdgcn_s_barrier();

    const char* Ab = (const char*)As[cur];
    const char* Bb = (const char*)Bs[cur];

    // plain reads; compiler interleaves with MFMAs via counted lgkmcnt
    short8 bfv[4][2], afv[8][2];
#pragma unroll
    for (int ni = 0; ni < 4; ni++)
#pragma unroll
      for (int ks = 0; ks < 2; ks++) {
        int r = wn * 64 + ni * 16 + l15;
        int c = ((ks << 2) | l4) ^ (r & 7);
        bfv[ni][ks] = *(const short8*)(Bb + r * 128 + c * 16);
      }
#pragma unroll
    for (int mi = 0; mi < 8; mi++)
#pragma unroll
      for (int ks = 0; ks < 2; ks++) {
        int r = wm * 128 + mi * 16 + l15;
        int c = ((ks << 2) | l4) ^ (r & 7);
        afv[mi][ks] = *(const short8*)(Ab + r * 128 + c * 16);
      }
#pragma unroll
    for (int ks = 0; ks < 2; ks++)
#pragma unroll
      for (int mi = 0; mi < 8; mi++) {
#pragma unroll
        for (int ni = 0; ni < 4; ni++)
          acc[mi][ni] = __builtin_amdgcn_mfma_f32_16x16x32_bf16(
              afv[mi][ks], bfv[ni][ks], acc[mi][ni], 0, 0, 0);
        if constexpr (MODE == 3)
          rsum[mi] = __builtin_amdgcn_mfma_f32_16x16x32_bf16(
              afv[mi][ks], ones, rsum[mi], 0, 0, 0);
      }
  }
#undef STAGE

  // epilogue
#pragma unroll
  for (int mi = 0; mi < 8; mi++) {
    float inv[4];
    if constexpr (MODE == 3) {
#pragma unroll
      for (int jj = 0; jj < 4; jj++) inv[jj] = 1.0f / rsum[mi][jj];
    }
#pragma unroll
    for (int ni = 0; ni < 4; ni++)
#pragma unroll
      for (int jj = 0; jj < 4; jj++) {
        int row = m0 + wm * 128 + mi * 16 + l4 * 4 + jj;
        int col = n0 + wn * 64 + ni * 16 + l15;
        float val = acc[mi][ni][jj];
        if constexpr (MODE == 1) {
          ((unsigned short*)Cb)[(size_t)row * ldc + col] = f2bf(val * scale);
        } else if constexpr (MODE == 2) {
          ((unsigned short*)Cb)[(size_t)row * ldc + col] =
              f2bf(__expf(val * scale));
        } else {
          ((float*)Cb)[(size_t)row * ldc + col] = val * inv[jj];
        }
      }
  }
}

// ---------- launcher ----------
extern "C" void kernel_launch(void* const* d_in, const int* in_sizes, int n_in,
                              void* d_out, int out_size, void* d_ws, size_t ws_size,
                              hipStream_t stream) {
  (void)in_sizes; (void)n_in; (void)out_size;
  const float* x  = (const float*)d_in[0];
  const float* Wq = (const float*)d_in[1];
  const float* Wk = (const float*)d_in[2];
  const float* Wv = (const float*)d_in[3];
  float* out = (float*)d_out;

  const int Bn = 4, S = 4096, D = 1024;
  const size_t MS = (size_t)Bn * S;  // 16384
  const float scale = 0.03125f;      // 1/sqrt(1024)

  // ---- workspace layout ----
  char* ws = (char*)d_ws;
  unsigned short* QKb = (unsigned short*)ws; ws += MS * 2048 * 2;        // 64 MiB
  unsigned short* VTb = (unsigned short*)ws; ws += MS * D * 2;           // 32 MiB
  unsigned short* Sreg = (unsigned short*)ws;
  const size_t s4_bytes = (size_t)Bn * S * S * 2;   // 128 MiB
  const size_t s1_bytes = (size_t)S * S * 2;        // 32 MiB
  size_t head = (size_t)(ws - (char*)d_ws);
  bool batched = ws_size >= head + s4_bytes + 6u * 1024 * 1024;
  ws += batched ? s4_bytes : s1_bytes;
  unsigned short* wqkb = (unsigned short*)ws; ws += (size_t)2048 * D * 2;
  unsigned short* wvb  = (unsigned short*)ws;
  unsigned short* xb = Sreg;  // alias: xb dead before any scores write

  // convert inputs to bf16
  cvt_f32_bf16<<<8192, 256, 0, stream>>>(x, xb, (long)MS * D);
  cvt_f32_bf16<<<512, 256, 0, stream>>>(Wq, wqkb, (long)D * D);
  cvt_f32_bf16<<<512, 256, 0, stream>>>(Wk, wqkb + (size_t)D * D, (long)D * D);
  cvt_f32_bf16<<<512, 256, 0, stream>>>(Wv, wvb, (long)D * D);

  // QK = x @ [Wq;Wk]^T  (M=16384, N=2048, K=1024)
  gemm_bt256<1><<<dim3(512, 1), 512, 0, stream>>>(
      xb, D, 0, wqkb, D, 0, QKb, 2048, 0, 8, D, 1.0f);
  // VT = Wv @ x^T  (M=1024, N=16384, K=1024) -> VTb [1024,16384]
  gemm_bt256<1><<<dim3(256, 1), 512, 0, stream>>>(
      wvb, D, 0, xb, D, 0, VTb, (int)MS, 0, 64, D, 1.0f);

  if (batched) {
    // P[b] = exp(Q_b K_b^T * scale)  (M=N=4096, K=1024) -> bf16
    gemm_bt256<2><<<dim3(256, Bn), 512, 0, stream>>>(
        QKb, 2048, (size_t)S * 2048,
        QKb + 1024, 2048, (size_t)S * 2048,
        Sreg, S, (size_t)S * S, 16, D, scale);
    // out[b] = (P_b @ V_b) / rowsum(P_b)  (M=4096, N=1024, K=4096)
    gemm_bt256<3><<<dim3(64, Bn), 512, 0, stream>>>(
        Sreg, S, (size_t)S * S,
        VTb, (int)MS, (size_t)S,
        out, D, (size_t)S * D, 4, S, 1.0f);
  } else {
    for (int b = 0; b < Bn; b++) {
      const unsigned short* Qx = QKb + (size_t)b * S * 2048;
      const unsigned short* Kx = Qx + 1024;
      gemm_bt256<2><<<dim3(256, 1), 512, 0, stream>>>(
          Qx, 2048, 0, Kx, 2048, 0, Sreg, S, 0, 16, D, scale);
      gemm_bt256<3><<<dim3(64, 1), 512, 0, stream>>>(
          Sreg, S, 0, VTb + (size_t)b * S, (int)MS, 0,
          out + (size_t)b * S * D, D, 0, 4, S, 1.0f);
    }
  }
}